// Round 12
// baseline (64.903 us; speedup 1.0000x reference)
//
#include <hip/hip_runtime.h>
#include <hip/hip_bf16.h>

// Problem: B=8192, DIM_IN=2048, DIM_OUT=512
//   hazards = relu(x @ W_h^T + b_h)            [8192,512]
//   out     = cumsum(hazards, axis=1) + (x @ W_base^T + b_base)
//
// Round 12: traffic reduction. Per-CU ingest is pinned at ~23 B/cyc across 8
// pipeline structures -> reduce bytes: BM=64 x BN=256 (grid 128x2=256).
// W aggregate 512->256 MB, x 64->128 MB; per-CU 2.25->1.5 MB. Cross-block
// scan carry via ws + tiny k_fix pass on the right half of out.

typedef __attribute__((ext_vector_type(8))) short  short8;
typedef __attribute__((ext_vector_type(4))) short  short4v;
typedef __attribute__((ext_vector_type(4))) float  float4v;
typedef __attribute__((ext_vector_type(4))) float  f32x4;

#define DIN  2048
#define DOUT 512
#define NROW 8192
#define BM   64
#define BN   256
#define NPH  (DIN / 64)   // 32 K-phases of 64

static __device__ __forceinline__ unsigned short f2bf(float f) {
  union { float f; unsigned int u; } v; v.f = f;
  unsigned int u = v.u;
  unsigned int r = (u + 0x7FFFu + ((u >> 16) & 1u)) >> 16;   // RNE
  return (unsigned short)r;
}

// barrier WITHOUT the vmcnt(0) drain __syncthreads would emit
static __device__ __forceinline__ void barrier_nd() {
  asm volatile("s_waitcnt lgkmcnt(0)" ::: "memory");
  __builtin_amdgcn_s_barrier();
}

// ---- k_pack: W[512][2048] f32 -> fragment-packed bf16 ---------------------
// fragment (nt, ktp): nt = n>>4 (32), ktp = k>>5 (64).
// lane slot: n = nt*16 + (lane&15), k = ktp*32 + (lane>>4)*8 (+e)
// storage: Wp[ ((nt*64 + ktp)*64 + lane)*8 + e ]  -> each frag = 1KB contig.
__global__ __launch_bounds__(256) void k_pack(const float* __restrict__ W,
                                              unsigned short* __restrict__ Wp) {
  int t    = blockIdx.x * 256 + threadIdx.x;   // 0..131071
  int lane = t & 63;
  int frag = t >> 6;
  int nt   = frag >> 6, ktp = frag & 63;
  int n = nt * 16 + (lane & 15);
  int k = ktp * 32 + (lane >> 4) * 8;
  const float* src = W + (size_t)n * DIN + k;
  float4v a = __builtin_nontemporal_load((const float4v*)src);
  float4v b = __builtin_nontemporal_load((const float4v*)(src + 4));
  unsigned short o[8] = { f2bf(a.x), f2bf(a.y), f2bf(a.z), f2bf(a.w),
                          f2bf(b.x), f2bf(b.y), f2bf(b.z), f2bf(b.w) };
  *(short8*)(Wp + (size_t)t * 8) = *(const short8*)o;
}

// ---- k_main: fused GEMM + bias + relu + partial row-scan ------------------
// grid 256: id -> bi = id>>1 (M-tile of 64), nj = id&1 (N-half of 256).
// 1024 threads = 16 waves arranged 2 (wr) x 8 (wc); wave tile 32x32.
// acc[mi][ni]: out rows wr*32+mi*16+(lane&15), cols wc*32+ni*16+(lane>>4)*4+r
// (swapped mfma: D[n][m], col slot = m). nj=0 also computes base GEMV and
// writes carry[row] = base + sum(left half) for k_fix.
__global__ __launch_bounds__(1024, 2) void k_main(
    const float* __restrict__ x, const unsigned short* __restrict__ Wp,
    const float* __restrict__ b_h, const float* __restrict__ w_base,
    const float* __restrict__ b_base, float* __restrict__ out,
    float* __restrict__ carryG) {
  __shared__ unsigned short Asw[2][BM * 64];   // 2 x 8 KB, XOR-swizzled
  __shared__ float WbL[DIN];                   // 8 KB base-GEMV weights
  __shared__ float stripT[BM][8];              // per-row per-wc strip totals
  __shared__ float baseL[BM];

  const int tid  = threadIdx.x;
  const int lane = tid & 63;
  const int w    = tid >> 6;       // wave 0..15
  const int wr   = w >> 3;         // 0..1  row-group
  const int wc   = w & 7;          // 0..7  col-strip
  const int q    = lane >> 4;      // 0..3
  const int lm   = lane & 15;
  const int id   = blockIdx.x;
  const int bi   = id >> 1, nj = id & 1;
  const int m0   = bi * BM;
  const bool isL = (nj == 0);

  // A staging: row sr = tid>>4 (0..63), seg = tid&15 (4 f32 at seg*4)
  const int sr  = tid >> 4;
  const int seg = tid & 15;
  const int sOff = sr * 64 + (((seg >> 1) ^ (sr & 7)) << 3) + (seg & 1) * 4;

  for (int i = tid; i < DIN; i += 1024) WbL[i] = w_base[i];

  f32x4 acc[2][2];
  const f32x4 z4 = {0.f, 0.f, 0.f, 0.f};
#pragma unroll
  for (int mi = 0; mi < 2; ++mi)
#pragma unroll
    for (int ni = 0; ni < 2; ++ni) acc[mi][ni] = z4;

  float4v a0, a1;
  short8  wf0[2][2], wf1[2][2];
  float   basePart = 0.f;

  auto loadA = [&](float4v& A, int kt) {
    A = __builtin_nontemporal_load(
        (const float4v*)(x + (size_t)(m0 + sr) * DIN + kt * 64 + seg * 4));
  };
  auto loadB = [&](short8 wf[2][2], int kt) {
#pragma unroll
    for (int ni = 0; ni < 2; ++ni)
#pragma unroll
      for (int h = 0; h < 2; ++h) {
        int nt   = nj * 16 + wc * 2 + ni;          // global 16-col group
        int frag = nt * 64 + (kt * 2 + h);
        wf[ni][h] = *(const short8*)(Wp + ((size_t)frag << 9) + lane * 8);
      }
  };
  auto writeA = [&](unsigned short* As, const float4v& A, int kt) {
    unsigned short t4[4] = { f2bf(A.x), f2bf(A.y), f2bf(A.z), f2bf(A.w) };
    *(short4v*)&As[sOff] = *(const short4v*)t4;
    float4v wb = *(const float4v*)&WbL[kt * 64 + seg * 4];
    basePart += A.x * wb.x + A.y * wb.y + A.z * wb.z + A.w * wb.w;
  };
  auto compute = [&](const unsigned short* As, const short8 wf[2][2]) {
#pragma unroll
    for (int h = 0; h < 2; ++h) {
      short8 xf[2];
#pragma unroll
      for (int mi = 0; mi < 2; ++mi) {
        int r = wr * 32 + mi * 16 + lm;
        int g = q + 4 * h;
        xf[mi] = *(const short8*)&As[r * 64 + ((g ^ (r & 7)) << 3)];
      }
#pragma unroll
      for (int mi = 0; mi < 2; ++mi)
#pragma unroll
        for (int ni = 0; ni < 2; ++ni)
          acc[mi][ni] = __builtin_amdgcn_mfma_f32_16x16x32_bf16(
              wf[ni][h], xf[mi], acc[mi][ni], 0, 0, 0);
    }
  };

  // prologue
  loadA(a0, 0); loadB(wf0, 0);
  loadA(a1, 1); loadB(wf1, 1);
  barrier_nd();                    // WbL ready (global prefetches in flight)
  writeA(Asw[0], a0, 0);
  barrier_nd();                    // tile 0 staged

  for (int kt = 0; kt < NPH; kt += 2) {
    if (kt + 2 < NPH) loadA(a0, kt + 2);
    compute(Asw[0], wf0);
    if (kt + 2 < NPH) loadB(wf0, kt + 2);
    writeA(Asw[1], a1, kt + 1);                  // kt+1 <= 31 always
    barrier_nd();
    if (kt + 3 < NPH) loadA(a1, kt + 3);
    compute(Asw[1], wf1);
    if (kt + 3 < NPH) loadB(wf1, kt + 3);
    if (kt + 2 < NPH) writeA(Asw[0], a0, kt + 2);
    barrier_nd();
  }

  // ---- base GEMV reduce: 16 consecutive threads share row sr ----
  {
    float s = basePart;
    s += __shfl_xor(s, 1); s += __shfl_xor(s, 2);
    s += __shfl_xor(s, 4); s += __shfl_xor(s, 8);
    if (seg == 0) baseL[sr] = s + b_base[0];
  }

  // ---- epilogue: bias + relu + scan over this wave's 32-col strip ----
  const int cb = nj * BN;          // global col base of this block
  float runp[2][2][4];
  float Eq[2][2];
  float niPre[2][2];
  float Tst[2];
#pragma unroll
  for (int mi = 0; mi < 2; ++mi) {
    float run = 0.f;
#pragma unroll
    for (int ni = 0; ni < 2; ++ni) {
      float4v b4 = *(const float4v*)(b_h + cb + wc * 32 + ni * 16 + q * 4);
      f32x4 v = acc[mi][ni];
      float h0 = fmaxf(v.x + b4.x, 0.f);
      float h1 = fmaxf(v.y + b4.y, 0.f);
      float h2 = fmaxf(v.z + b4.z, 0.f);
      float h3 = fmaxf(v.w + b4.w, 0.f);
      runp[mi][ni][0] = h0;
      runp[mi][ni][1] = h0 + h1;
      runp[mi][ni][2] = h0 + h1 + h2;
      runp[mi][ni][3] = h0 + h1 + h2 + h3;
      float S = runp[mi][ni][3];
      float u1 = __shfl_up(S, 16);
      float u2 = __shfl_up(S, 32);
      float u3 = __shfl_up(S, 48);
      Eq[mi][ni] = (q >= 1 ? u1 : 0.f) + (q >= 2 ? u2 : 0.f) + (q >= 3 ? u3 : 0.f);
      float G = S + __shfl_xor(S, 16);
      G += __shfl_xor(G, 32);
      niPre[mi][ni] = run;
      run += G;
    }
    Tst[mi] = run;
  }
  if (q == 0) {
#pragma unroll
    for (int mi = 0; mi < 2; ++mi) stripT[wr * 32 + mi * 16 + lm][wc] = Tst[mi];
  }
  barrier_nd();

#pragma unroll
  for (int mi = 0; mi < 2; ++mi) {
    const int row = wr * 32 + mi * 16 + lm;
    float c = isL ? baseL[row] : 0.f;        // left half starts at base
    float4v sA = *(const float4v*)&stripT[row][0];
    float4v sB = *(const float4v*)&stripT[row][4];
    c += (wc > 0 ? sA.x : 0.f) + (wc > 1 ? sA.y : 0.f) + (wc > 2 ? sA.z : 0.f) +
         (wc > 3 ? sA.w : 0.f) + (wc > 4 ? sB.x : 0.f) + (wc > 5 ? sB.y : 0.f) +
         (wc > 6 ? sB.z : 0.f);
    // carry for the right half: base + total of left 256 cols
    if (isL && wc == 7 && q == 0) carryG[m0 + row] = c + Tst[mi];
#pragma unroll
    for (int ni = 0; ni < 2; ++ni) {
      float base = c + niPre[mi][ni] + Eq[mi][ni];
      float4v o = { runp[mi][ni][0] + base, runp[mi][ni][1] + base,
                    runp[mi][ni][2] + base, runp[mi][ni][3] + base };
      __builtin_nontemporal_store(
          o, (float4v*)(out + (size_t)(m0 + row) * DOUT + cb + wc * 32 + ni * 16 + q * 4));
    }
  }
}

// ---- k_fix: out[row][256..511] += carry[row] ------------------------------
// 64 threads per row (4 cols each); fully coalesced float4 RMW.
__global__ __launch_bounds__(256) void k_fix(float* __restrict__ out,
                                             const float* __restrict__ carry) {
  int idx = blockIdx.x * 256 + threadIdx.x;     // 0..524287
  int row = idx >> 6;
  int c4  = (idx & 63) * 4 + BN;
  float cr = carry[row];
  float4v* p = (float4v*)(out + (size_t)row * DOUT + c4);
  float4v v = *p;
  v.x += cr; v.y += cr; v.z += cr; v.w += cr;
  __builtin_nontemporal_store(v, p);
}

// ---------------------------------------------------------------------------
extern "C" void kernel_launch(void* const* d_in, const int* in_sizes, int n_in,
                              void* d_out, int out_size, void* d_ws, size_t ws_size,
                              hipStream_t stream) {
  const float* x   = (const float*)d_in[0];  // [8192,2048]
  const float* Wh  = (const float*)d_in[1];  // [512,2048]
  const float* bh  = (const float*)d_in[2];  // [512]
  const float* Wb0 = (const float*)d_in[3];  // [1,2048]
  const float* bb  = (const float*)d_in[4];  // [1]
  float* out = (float*)d_out;

  char* ws = (char*)d_ws;
  unsigned short* Wp = (unsigned short*)ws;              // 2 MiB packed W
  float* carry       = (float*)(ws + 2u * 1024 * 1024);  // 32 KiB

  k_pack<<<dim3((DOUT * DIN) / (256 * 8)), dim3(256), 0, stream>>>(Wh, Wp);
  k_main<<<dim3((NROW / BM) * (DOUT / BN)), dim3(1024), 0, stream>>>(
      x, Wp, bh, Wb0, bb, out, carry);
  k_fix<<<dim3(NROW * (DOUT - BN) / 4 / 256), dim3(256), 0, stream>>>(out, carry);
}

// Round 13
// 43.615 us; speedup vs baseline: 1.4881x; 1.4881x over previous
//
#include <hip/hip_runtime.h>
#include <hip/hip_bf16.h>

// Problem: B=8192, DIM_IN=2048, DIM_OUT=512
//   hazards = relu(x @ W_h^T + b_h)            [8192,512]
//   out     = cumsum(hazards, axis=1) + (x @ W_base^T + b_base)
//
// Round 13: r11 kernel + PER-BLOCK K-PHASE ROTATION. All blocks read the
// identical W slice in the same order while barrier-locked -> all CUs of an
// XCD hammer the same L2 lines simultaneously (no multicast) -> hot-channel
// convoy pins delivery at ~1.6 TB/s. Rotate each block's K order by
// off = (blockIdx>>3)&31 so the 32 CUs per XCD stream 32 different W slices.
// MFMA accumulation is K-order-independent; correctness unchanged.

typedef __attribute__((ext_vector_type(8))) short  short8;
typedef __attribute__((ext_vector_type(4))) short  short4v;
typedef __attribute__((ext_vector_type(4))) float  float4v;
typedef __attribute__((ext_vector_type(4))) float  f32x4;

#define DIN  2048
#define DOUT 512
#define NROW 8192
#define BM   32
#define NPH  (DIN / 64)   // 32 K-phases of 64

static __device__ __forceinline__ unsigned short f2bf(float f) {
  union { float f; unsigned int u; } v; v.f = f;
  unsigned int u = v.u;
  unsigned int r = (u + 0x7FFFu + ((u >> 16) & 1u)) >> 16;   // RNE
  return (unsigned short)r;
}

// barrier WITHOUT the vmcnt(0) drain __syncthreads would emit
static __device__ __forceinline__ void barrier_nd() {
  asm volatile("s_waitcnt lgkmcnt(0)" ::: "memory");
  __builtin_amdgcn_s_barrier();
}

// ---- k_pack: W[512][2048] f32 -> fragment-packed bf16 ---------------------
// fragment (nt, ktp): nt = n>>4 (32), ktp = k>>5 (64).
// lane slot: n = nt*16 + (lane&15), k = ktp*32 + (lane>>4)*8 (+e)
// storage: Wp[ ((nt*64 + ktp)*64 + lane)*8 + e ]  -> wave load = 1KB contig.
__global__ __launch_bounds__(256) void k_pack(const float* __restrict__ W,
                                              unsigned short* __restrict__ Wp) {
  int t    = blockIdx.x * 256 + threadIdx.x;   // 0..131071
  int lane = t & 63;
  int frag = t >> 6;
  int nt   = frag >> 6, ktp = frag & 63;
  int n = nt * 16 + (lane & 15);
  int k = ktp * 32 + (lane >> 4) * 8;
  const float* src = W + (size_t)n * DIN + k;
  float4v a = __builtin_nontemporal_load((const float4v*)src);
  float4v b = __builtin_nontemporal_load((const float4v*)(src + 4));
  unsigned short o[8] = { f2bf(a.x), f2bf(a.y), f2bf(a.z), f2bf(a.w),
                          f2bf(b.x), f2bf(b.y), f2bf(b.z), f2bf(b.w) };
  *(short8*)(Wp + (size_t)t * 8) = *(const short8*)o;
}

// ---- k_main: fused GEMM + bias + relu + row-scan + base -------------------
// grid 256 (BM=32 rows each), 1024 threads = 16 waves; wave w owns cols
// 32w..32w+31 (ni 0..1 -> nt = 2w+ni). acc[mi][ni]: rows mi*16+(lane&15),
// cols ni*16 + (lane>>4)*4 + reg.   (swapped mfma: D[n][m], col slot = m)
__global__ __launch_bounds__(1024, 4) void k_main(
    const float* __restrict__ x, const unsigned short* __restrict__ Wp,
    const float* __restrict__ b_h, const float* __restrict__ w_base,
    const float* __restrict__ b_base, float* __restrict__ out) {
  __shared__ unsigned short Asw[2][BM * 64];   // 2 x 4 KB, XOR-swizzled
  __shared__ float WbL[DIN];                   // 8 KB base-GEMV weights
  __shared__ float stripT[BM][16];             // per-row per-wave strip totals
  __shared__ float baseL[BM];

  const int tid  = threadIdx.x;
  const int lane = tid & 63;
  const int w    = tid >> 6;       // wave 0..15
  const int q    = lane >> 4;      // 0..3
  const int lm   = lane & 15;
  const int m0   = blockIdx.x * BM;
  const bool stager = (tid < 512); // waves 0..7 stage A + base GEMV

  // per-block K-phase rotation: 32 CUs of an XCD get 32 distinct offsets
  const int off = (blockIdx.x >> 3) & 31;

  // A staging (tid<512): row sr = tid>>4 (0..31), seg = tid&15 (4 f32)
  const int sr  = tid >> 4;
  const int seg = tid & 15;
  const int sOff = (sr & 31) * 64 + (((seg >> 1) ^ (sr & 7)) << 3) + (seg & 1) * 4;

  for (int i = tid; i < DIN; i += 1024) WbL[i] = w_base[i];

  f32x4 acc[2][2];
  const f32x4 z4 = {0.f, 0.f, 0.f, 0.f};
#pragma unroll
  for (int mi = 0; mi < 2; ++mi)
#pragma unroll
    for (int ni = 0; ni < 2; ++ni) acc[mi][ni] = z4;

  float4v a0, a1;
  short8  wf0[2][2], wf1[2][2];
  float   basePart = 0.f;

  // logical phase kt -> physical phase pk = (kt + off) & 31
  auto loadA = [&](float4v& A, int kt) {
    if (stager) {
      const int pk = (kt + off) & (NPH - 1);
      A = __builtin_nontemporal_load(
          (const float4v*)(x + (size_t)(m0 + sr) * DIN + pk * 64 + seg * 4));
    }
  };
  auto loadB = [&](short8 wf[2][2], int kt) {
    const int pk = (kt + off) & (NPH - 1);
#pragma unroll
    for (int ni = 0; ni < 2; ++ni)
#pragma unroll
      for (int h = 0; h < 2; ++h) {
        int frag = (w * 2 + ni) * 64 + (pk * 2 + h);
        wf[ni][h] = *(const short8*)(Wp + ((size_t)frag << 9) + lane * 8);
      }
  };
  auto writeA = [&](unsigned short* As, const float4v& A, int kt) {
    if (stager) {
      const int pk = (kt + off) & (NPH - 1);
      unsigned short t4[4] = { f2bf(A.x), f2bf(A.y), f2bf(A.z), f2bf(A.w) };
      *(short4v*)&As[sOff] = *(const short4v*)t4;
      float4v wb = *(const float4v*)&WbL[pk * 64 + seg * 4];
      basePart += A.x * wb.x + A.y * wb.y + A.z * wb.z + A.w * wb.w;
    }
  };
  auto compute = [&](const unsigned short* As, const short8 wf[2][2]) {
#pragma unroll
    for (int h = 0; h < 2; ++h) {
      short8 xf[2];
#pragma unroll
      for (int mi = 0; mi < 2; ++mi) {
        int r = mi * 16 + lm;
        int g = q + 4 * h;
        xf[mi] = *(const short8*)&As[r * 64 + ((g ^ (r & 7)) << 3)];
      }
#pragma unroll
      for (int mi = 0; mi < 2; ++mi)
#pragma unroll
        for (int ni = 0; ni < 2; ++ni)
          acc[mi][ni] = __builtin_amdgcn_mfma_f32_16x16x32_bf16(
              wf[ni][h], xf[mi], acc[mi][ni], 0, 0, 0);
    }
  };

  // prologue
  loadA(a0, 0); loadB(wf0, 0);
  loadA(a1, 1); loadB(wf1, 1);
  barrier_nd();                    // WbL ready (global prefetches in flight)
  writeA(Asw[0], a0, 0);
  barrier_nd();                    // tile 0 staged

  for (int kt = 0; kt < NPH; kt += 2) {
    // phase A: compute tile kt from buf0 + wf0
    if (kt + 2 < NPH) loadA(a0, kt + 2);
    compute(Asw[0], wf0);
    if (kt + 2 < NPH) loadB(wf0, kt + 2);
    writeA(Asw[1], a1, kt + 1);                  // kt+1 <= 31 always
    barrier_nd();
    // phase B: compute tile kt+1 from buf1 + wf1
    if (kt + 3 < NPH) loadA(a1, kt + 3);
    compute(Asw[1], wf1);
    if (kt + 3 < NPH) loadB(wf1, kt + 3);
    if (kt + 2 < NPH) writeA(Asw[0], a0, kt + 2);
    barrier_nd();
  }

  // ---- base GEMV reduce: 16 consecutive threads share row sr ----
  if (stager) {
    float s = basePart;
    s += __shfl_xor(s, 1); s += __shfl_xor(s, 2);
    s += __shfl_xor(s, 4); s += __shfl_xor(s, 8);
    if (seg == 0) baseL[sr] = s + b_base[0];
  }

  // ---- epilogue: bias + relu + scan over this wave's 32-col strip ----
  float runp[2][2][4];   // inclusive in-run (4-col) prefix
  float Eq[2][2];        // sum of runs with smaller q (same 16-col group)
  float niPre[2][2];     // sum of full 16-col groups with smaller ni
  float Tst[2];          // strip total per row
#pragma unroll
  for (int mi = 0; mi < 2; ++mi) {
    float run = 0.f;
#pragma unroll
    for (int ni = 0; ni < 2; ++ni) {
      float4v b4 = *(const float4v*)(b_h + w * 32 + ni * 16 + q * 4);
      f32x4 v = acc[mi][ni];
      float h0 = fmaxf(v.x + b4.x, 0.f);
      float h1 = fmaxf(v.y + b4.y, 0.f);
      float h2 = fmaxf(v.z + b4.z, 0.f);
      float h3 = fmaxf(v.w + b4.w, 0.f);
      runp[mi][ni][0] = h0;
      runp[mi][ni][1] = h0 + h1;
      runp[mi][ni][2] = h0 + h1 + h2;
      runp[mi][ni][3] = h0 + h1 + h2 + h3;
      float S = runp[mi][ni][3];
      float u1 = __shfl_up(S, 16);
      float u2 = __shfl_up(S, 32);
      float u3 = __shfl_up(S, 48);
      Eq[mi][ni] = (q >= 1 ? u1 : 0.f) + (q >= 2 ? u2 : 0.f) + (q >= 3 ? u3 : 0.f);
      float G = S + __shfl_xor(S, 16);
      G += __shfl_xor(G, 32);
      niPre[mi][ni] = run;
      run += G;
    }
    Tst[mi] = run;
  }
  if (q == 0) {
#pragma unroll
    for (int mi = 0; mi < 2; ++mi) stripT[mi * 16 + lm][w] = Tst[mi];
  }
  barrier_nd();

#pragma unroll
  for (int mi = 0; mi < 2; ++mi) {
    const int row = mi * 16 + lm;
    float c = baseL[row];
#pragma unroll
    for (int j4 = 0; j4 < 4; ++j4) {
      float4v s = *(const float4v*)&stripT[row][j4 * 4];
      c += (w > j4 * 4 + 0 ? s.x : 0.f) + (w > j4 * 4 + 1 ? s.y : 0.f) +
           (w > j4 * 4 + 2 ? s.z : 0.f) + (w > j4 * 4 + 3 ? s.w : 0.f);
    }
#pragma unroll
    for (int ni = 0; ni < 2; ++ni) {
      float base = c + niPre[mi][ni] + Eq[mi][ni];
      float4v o = { runp[mi][ni][0] + base, runp[mi][ni][1] + base,
                    runp[mi][ni][2] + base, runp[mi][ni][3] + base };
      __builtin_nontemporal_store(
          o, (float4v*)(out + (size_t)(m0 + row) * DOUT + w * 32 + ni * 16 + q * 4));
    }
  }
}

// ---------------------------------------------------------------------------
extern "C" void kernel_launch(void* const* d_in, const int* in_sizes, int n_in,
                              void* d_out, int out_size, void* d_ws, size_t ws_size,
                              hipStream_t stream) {
  const float* x   = (const float*)d_in[0];  // [8192,2048]
  const float* Wh  = (const float*)d_in[1];  // [512,2048]
  const float* bh  = (const float*)d_in[2];  // [512]
  const float* Wb0 = (const float*)d_in[3];  // [1,2048]
  const float* bb  = (const float*)d_in[4];  // [1]
  float* out = (float*)d_out;

  unsigned short* Wp = (unsigned short*)d_ws;   // 2 MiB fragment-packed W

  k_pack<<<dim3((DOUT * DIN) / (256 * 8)), dim3(256), 0, stream>>>(Wh, Wp);
  k_main<<<dim3(NROW / BM), dim3(1024), 0, stream>>>(x, Wp, bh, Wb0, bb, out);
}